// Round 4
// baseline (286.328 us; speedup 1.0000x reference)
//
#include <hip/hip_runtime.h>
#include <hip/hip_fp16.h>
#include <math.h>

// FBP adjoint: out[b,i0,i1,i2] = (1/A) * sum_j lerp(x[b,j,i1,:], ix(j,i0,i2))
//   ix = 16 + (i2-16)*cos(a_j) + (i0-16)*sin(a_j); y-interp exact (iy==i1).
//
// R4 (= R3 + type fix): loop inversion to amortize weight math. Thread owns
// n=(i0,i2), block owns (b, i1-pair): each (kp,w0,w1) computation feeds TWO
// m's. Lerp = one v_dot2_f32_f16 (fp16 pair . fp16 weights + fp32 acc).
// cos/sin from a precomputed global table (pre-kernel into d_ws) ->
// wave-uniform load, keeping the LDS pipe for pair reads only.
// LDS: staggered fp16-pair rows pr[j][sel][p], p in [0,46): (row[p-7],row[p-6]),
// zero-padded => OOB corners contribute 0 exactly like reference's w*valid.

#define PDIM  33
#define PP    1089
#define A_    121
#define ROWW  48              // dwords per (j,sel) row (46 used, pad to 48)
#define NPAIR 46
#define PADL  7
#define BLK   384
#define NV    3               // 3*384 = 1152 slots for 1089 n's
#define HPB   17              // i1-pairs per b (ceil 33/2)

typedef _Float16 h2v __attribute__((ext_vector_type(2)));

#if defined(__has_builtin)
#if __has_builtin(__builtin_amdgcn_fractf)
#define FRACTF(x) __builtin_amdgcn_fractf(x)
#endif
#endif
#ifndef FRACTF
#define FRACTF(x) ((x) - floorf(x))
#endif

__global__ void cs_kernel(const float* __restrict__ angles,
                          float2* __restrict__ csw, int A)
{
    int j = threadIdx.x;
    if (j < A) {
        float s, c;
        sincosf(angles[j], &s, &c);
        csw[j] = make_float2(c, s);
    }
}

__device__ __forceinline__ float fdot2f(h2v a, h2v b, float c)
{
#if defined(__has_builtin) && __has_builtin(__builtin_amdgcn_fdot2)
    return __builtin_amdgcn_fdot2(a, b, c, false);
#else
    return fmaf((float)a.x, (float)b.x, fmaf((float)a.y, (float)b.y, c));
#endif
}

__device__ __forceinline__ h2v pack2h(float lo, float hi)
{
    return __builtin_bit_cast(h2v, __builtin_amdgcn_cvt_pkrtz(lo, hi));
}

__global__ __launch_bounds__(BLK)
void fbp_adjoint_kernel(const float* __restrict__ x,
                        const float2* __restrict__ csw,     // may be null
                        const float* __restrict__ angles,   // fallback
                        float* __restrict__ out,
                        float invA)
{
    __shared__ h2v    pr[A_ * 2 * ROWW];  // 121*96 dwords = 46.5 KB
    __shared__ float2 cs_lds[A_];         // fallback table (ws too small)

    const int t   = threadIdx.x;
    const int blk = blockIdx.x;           // blk = b*17 + h
    const int b   = blk / HPB;
    const int h   = blk - b * HPB;
    const int i1a = 2 * h;
    const int i1b = i1a + 1;
    const bool has2 = (i1b < PDIM);

    const bool use_ws = (csw != nullptr);
    if (!use_ws) {
        for (int j = t; j < A_; j += BLK) {
            float s, c;
            sincosf(angles[j], &s, &c);
            cs_lds[j] = make_float2(c, s);
        }
    }

    // Stage staggered fp16 pairs for rows (b, j, i1a) and (b, j, i1b).
    const float* xb = x + (size_t)b * (A_ * PP);
    for (int e = t; e < A_ * 2 * NPAIR; e += BLK) {
        int j   = e / (2 * NPAIR);
        int r   = e - j * (2 * NPAIR);
        int sel = r / NPAIR;
        int p   = r - sel * NPAIR;
        int i1  = has2 ? (i1a + sel) : i1a;   // clamp (dup row; never stored)
        const float* row = xb + (size_t)j * PP + i1 * PDIM;
        int k = p - PADL;
        float lo = (k     >= 0 && k     < PDIM) ? row[k]     : 0.0f;
        float hi = (k + 1 >= 0 && k + 1 < PDIM) ? row[k + 1] : 0.0f;
        pr[j * (2 * ROWW) + sel * ROWW + p] = pack2h(lo, hi);
    }
    __syncthreads();

    float u0[NV], u2[NV], acc0[NV], acc1[NV];
#pragma unroll
    for (int nn = 0; nn < NV; ++nn) {
        int n  = t + nn * BLK;
        int nc = (n < PP) ? n : (PP - 1);
        int q0 = nc / PDIM;
        int q2 = nc - q0 * PDIM;
        u0[nn] = (float)(q0 - 16);
        u2[nn] = (float)(q2 - 16);
        acc0[nn] = 0.0f;
        acc1[nn] = 0.0f;
    }

#pragma unroll 2
    for (int j = 0; j < A_; ++j) {
        float2 cj = use_ws ? csw[j] : cs_lds[j];
        const h2v* base = &pr[j * (2 * ROWW)];
#pragma unroll
        for (int nn = 0; nn < NV; ++nn) {
            // ixp = ix + 7 in [0.37, 45.63]
            float ixp = fmaf(u2[nn], cj.x, fmaf(u0[nn], cj.y, 23.0f));
            int   kp  = (int)ixp;            // trunc == floor (positive)
            float w1  = FRACTF(ixp);
            h2v   w   = pack2h(1.0f - w1, w1);
            h2v   v0  = base[kp];            // row i1a pair
            h2v   v1  = base[ROWW + kp];     // row i1b pair
            acc0[nn] = fdot2f(v0, w, acc0[nn]);
            acc1[nn] = fdot2f(v1, w, acc1[nn]);
        }
    }

    // out[b, i0, i1, i2] = out[b*35937 + i0*1089 + i1*33 + i2]
    float* ob = out + (size_t)b * (PDIM * PP);
#pragma unroll
    for (int nn = 0; nn < NV; ++nn) {
        int n = t + nn * BLK;
        if (n < PP) {
            int q0 = n / PDIM;
            int q2 = n - q0 * PDIM;
            size_t o = (size_t)q0 * PP + q2;
            ob[o + (size_t)i1a * PDIM] = acc0[nn] * invA;
            if (has2) ob[o + (size_t)i1b * PDIM] = acc1[nn] * invA;
        }
    }
}

extern "C" void kernel_launch(void* const* d_in, const int* in_sizes, int n_in,
                              void* d_out, int out_size, void* d_ws, size_t ws_size,
                              hipStream_t stream)
{
    const float* x      = (const float*)d_in[0];
    const float* angles = (const float*)d_in[1];
    float* out          = (float*)d_out;

    const int A = in_sizes[1];                    // 121
    const int B = in_sizes[0] / (A * PP);         // 128

    float2* csw = nullptr;
    if (ws_size >= sizeof(float2) * (size_t)A) {
        csw = (float2*)d_ws;
        cs_kernel<<<1, 128, 0, stream>>>(angles, csw, A);
    }

    dim3 grid(B * HPB);
    dim3 block(BLK);
    fbp_adjoint_kernel<<<grid, block, 0, stream>>>(x, csw, angles, out,
                                                   1.0f / (float)A);
}

// Round 5
// 213.275 us; speedup vs baseline: 1.3425x; 1.3425x over previous
//
#include <hip/hip_runtime.h>
#include <hip/hip_fp16.h>
#include <math.h>

// FBP adjoint: out[b,i0,i1,i2] = (1/A) * sum_j lerp(x[b,j,i1,:], ix(j,i0,i2))
//   ix = 16 + (i2-16)*cos(a_j) + (i0-16)*sin(a_j); y-interp exact (iy==i1).
//
// R5: b-pair amortization with INTERLEAVED fp16 rows (no stagger duplication).
// Block owns (b-pair, i1); LDS dr[j][p] = (half(x[b0,j,i1,p-7]), half(x[b1,...]))
// zero-padded p in [0,47) => OOB corners contribute 0 (matches w*valid).
// One ds_read2_b32 (adjacent dwords kp,kp+1) fetches all 4 corner values for
// both b's; lerp via v_fma_mix_f32 (compiler folds half->float cvt into fma),
// weights stay fp32 (better precision than R2/R4's fp16 weights).
// LDS 22.7KB (vs R4's 46.5KB which killed occupancy) -> ~5 blocks/CU.

#define PDIM 33
#define PP   1089
#define A_   121
#define ROWW 47              // padded row: k in [-7,39] -> p = k+7 in [0,47)
#define PADL 7
#define BLK  384
#define NV   3               // 3*384 = 1152 slots for 1089 n's

#if defined(__has_builtin)
#if __has_builtin(__builtin_amdgcn_fractf)
#define FRACTF(x) __builtin_amdgcn_fractf(x)
#endif
#endif
#ifndef FRACTF
#define FRACTF(x) ((x) - floorf(x))
#endif

__global__ void cs_kernel(const float* __restrict__ angles,
                          float2* __restrict__ csw, int A)
{
    int j = threadIdx.x;
    if (j < A) {
        float s, c;
        sincosf(angles[j], &s, &c);
        csw[j] = make_float2(c, s);
    }
}

__global__ __launch_bounds__(BLK)
void fbp_adjoint_kernel(const float* __restrict__ x,
                        const float2* __restrict__ csw,     // may be null
                        const float* __restrict__ angles,   // fallback
                        float* __restrict__ out,
                        float invA)
{
    __shared__ __half2 dr[A_ * ROWW];     // 121*47*4B = 22.7 KB
    __shared__ float2  cs_lds[A_];        // fallback table

    const int t   = threadIdx.x;
    const int blk = blockIdx.x;           // blk = hb*33 + i1
    const int hb  = blk / PDIM;
    const int i1  = blk - hb * PDIM;
    const int b0  = 2 * hb;

    const bool use_ws = (csw != nullptr);
    if (!use_ws) {
        for (int j = t; j < A_; j += BLK) {
            float s, c;
            sincosf(angles[j], &s, &c);
            cs_lds[j] = make_float2(c, s);
        }
    }

    // Stage interleaved fp16 rows for (b0, i1) and (b0+1, i1).
    const float* r0 = x + (size_t)b0 * (A_ * PP) + (size_t)i1 * PDIM;
    const float* r1 = r0 + (size_t)(A_ * PP);    // b1 = b0+1
    for (int e = t; e < A_ * ROWW; e += BLK) {
        int j = e / ROWW;
        int p = e - j * ROWW;
        int k = p - PADL;
        float f0 = 0.0f, f1 = 0.0f;
        if (k >= 0 && k < PDIM) {
            size_t o = (size_t)j * PP + k;
            f0 = r0[o];
            f1 = r1[o];
        }
        dr[e] = __halves2half2(__float2half_rn(f0), __float2half_rn(f1));
    }
    __syncthreads();

    float u0[NV], u2[NV], a0[NV], a1[NV];
#pragma unroll
    for (int nn = 0; nn < NV; ++nn) {
        int n  = t + nn * BLK;
        int nc = (n < PP) ? n : (PP - 1);
        int q0 = nc / PDIM;
        int q2 = nc - q0 * PDIM;
        u0[nn] = (float)(q0 - 16);
        u2[nn] = (float)(q2 - 16);
        a0[nn] = 0.0f;
        a1[nn] = 0.0f;
    }

#pragma unroll 2
    for (int j = 0; j < A_; ++j) {
        float2 cj = use_ws ? csw[j] : cs_lds[j];
        const __half2* base = &dr[j * ROWW];
#pragma unroll
        for (int nn = 0; nn < NV; ++nn) {
            // ixp = ix + 7 in [0.37, 45.63]; kp in [0,45], kp+1 <= 46 < ROWW
            float ixp = fmaf(u2[nn], cj.x, fmaf(u0[nn], cj.y, 23.0f));
            int   kp  = (int)ixp;            // trunc == floor (positive)
            float w1  = FRACTF(ixp);
            float w0  = 1.0f - w1;
            __half2 d0 = base[kp];           // (v_k^b0,  v_k^b1)
            __half2 d1 = base[kp + 1];       // (v_k1^b0, v_k1^b1)  -> ds_read2
            a0[nn] = fmaf(__half2float(__low2half(d0)),  w0, a0[nn]);
            a0[nn] = fmaf(__half2float(__low2half(d1)),  w1, a0[nn]);
            a1[nn] = fmaf(__half2float(__high2half(d0)), w0, a1[nn]);
            a1[nn] = fmaf(__half2float(__high2half(d1)), w1, a1[nn]);
        }
    }

    // out[b, i0, i1, i2] = out[b*35937 + i0*1089 + i1*33 + i2]
    float* ob0 = out + (size_t)b0 * (PDIM * PP) + (size_t)i1 * PDIM;
    float* ob1 = ob0 + (size_t)(PDIM * PP);
#pragma unroll
    for (int nn = 0; nn < NV; ++nn) {
        int n = t + nn * BLK;
        if (n < PP) {
            int q0 = n / PDIM;
            int q2 = n - q0 * PDIM;
            size_t o = (size_t)q0 * PP + q2;
            ob0[o] = a0[nn] * invA;
            ob1[o] = a1[nn] * invA;
        }
    }
}

extern "C" void kernel_launch(void* const* d_in, const int* in_sizes, int n_in,
                              void* d_out, int out_size, void* d_ws, size_t ws_size,
                              hipStream_t stream)
{
    const float* x      = (const float*)d_in[0];
    const float* angles = (const float*)d_in[1];
    float* out          = (float*)d_out;

    const int A = in_sizes[1];                    // 121
    const int B = in_sizes[0] / (A * PP);         // 128

    float2* csw = nullptr;
    if (ws_size >= sizeof(float2) * (size_t)A) {
        csw = (float2*)d_ws;
        cs_kernel<<<1, 128, 0, stream>>>(angles, csw, A);
    }

    dim3 grid((B / 2) * PDIM);                    // 64 b-pairs * 33 i1 = 2112
    dim3 block(BLK);
    fbp_adjoint_kernel<<<grid, block, 0, stream>>>(x, csw, angles, out,
                                                   1.0f / (float)A);
}